// Round 3
// baseline (207.642 us; speedup 1.0000x reference)
//
#include <hip/hip_runtime.h>
#include <stdint.h>

#define BB 8
#define NN 2048
#define CC 64
#define KK 32
#define DK 16
#define RADIUSF 0.2f
#define EPSF 1e-8f
#define BN_EPSF 1e-5f

typedef unsigned long long u64;
typedef unsigned int u32;

// --- fp32 helpers matching the reference's arithmetic ---
// sum of squares: elementwise square (rounded) then sequential reduce — no FMA
__device__ __forceinline__ float refsq3(float a, float b, float c) {
  return __fadd_rn(__fadd_rn(__fmul_rn(a, a), __fmul_rn(b, b)), __fmul_rn(c, c));
}
// einsum dot: BLAS/Eigen/XLA style acc = fma(a_k, b_k, acc), k ascending, acc0=0
__device__ __forceinline__ float refdot3(float ax, float ay, float az,
                                         float bx, float by, float bz) {
  return __builtin_fmaf(az, bz, __builtin_fmaf(ay, by, __fmul_rn(ax, bx)));
}
__device__ __forceinline__ float refdist(float sx, float sy, float dt) {
  float d2 = __fsub_rn(__fadd_rn(sx, sy), __fmul_rn(2.0f, dt));
  d2 = fmaxf(d2, 0.0f);
  return d2 > 0.0f ? __fsqrt_rn(d2) : 0.0f;
}

// ---------------------------------------------------------------------------
// Kernel 1: G[b][n][c] = inv[c]*(W_f[c,:]·feats[b,:,n]) + shift[c]
// layout G: (B*N, 64) so agg gathers are 256B-contiguous rows.
// ---------------------------------------------------------------------------
__global__ __launch_bounds__(256) void gfeat_kernel(
    const float* __restrict__ feats, const float* __restrict__ conv_w,
    const float* __restrict__ gamma, const float* __restrict__ beta,
    const float* __restrict__ mean, const float* __restrict__ var,
    float* __restrict__ G) {
  int t = blockIdx.x * 256 + threadIdx.x;   // t = m*64 + c
  int c = t & 63;
  int m = t >> 6;                            // b*N + n
  int b = m >> 11;
  int n = m & (NN - 1);
  float inv = __fdiv_rn(gamma[c], __fsqrt_rn(__fadd_rn(var[c], BN_EPSF)));
  float shift = __fsub_rn(beta[c], __fmul_rn(mean[c], inv));
  const float* f = feats + (size_t)b * CC * NN + n;   // stride NN over c'
  const float* w = conv_w + c * (CC + 3) + 3;
  float acc = 0.f;
#pragma unroll
  for (int cp = 0; cp < CC; ++cp) acc = fmaf(w[cp], f[(size_t)cp * NN], acc);
  G[t] = fmaf(inv, acc, shift);
}

// ---------------------------------------------------------------------------
// Kernel 2: exact KNN (== reference ball query: the in-radius prefix equals
// the KNN prefix and fallback slots are knn_idx at the same positions, so
// idx == knn_idx exactly). Selection key = (bits(f32 sqrt dist) << 32) | j:
// post-sqrt compare (sqrt creates ties the ref breaks by index), dot with
// FMA-LTR to bit-match the reference's f32 einsum.
// ---------------------------------------------------------------------------
__global__ __launch_bounds__(64) void knn_kernel(const float* __restrict__ coords,
                                                 int* __restrict__ idx_out) {
  __shared__ u64 lds[64 * 33 + 32];   // 33 slots/lane: 32 sorted keys + sentinel
  const int lane = threadIdx.x;
  const int pid = blockIdx.x;          // b*N + i
  const int b = pid >> 11;
  const int i = pid & (NN - 1);
  const float* cb = coords + (size_t)b * NN * 3;
  float cx = cb[i * 3 + 0], cy = cb[i * 3 + 1], cz = cb[i * 3 + 2];
  float sxi = refsq3(cx, cy, cz);

  u64 key[32];
#pragma unroll
  for (int c = 0; c < 32; ++c) {
    int j = c * 64 + lane;
    float px = cb[j * 3 + 0], py = cb[j * 3 + 1], pz = cb[j * 3 + 2];
    float syj = refsq3(px, py, pz);
    float dt = refdot3(cx, cy, cz, px, py, pz);
    float d = refdist(sxi, syj, dt);
    key[c] = ((u64)__float_as_uint(d) << 32) | (u32)j;
  }

  // Batcher odd-even mergesort, n=32, ascending, static indices (stays in VGPRs)
#pragma unroll
  for (int p = 1; p < 32; p <<= 1) {
#pragma unroll
    for (int k = p; k >= 1; k >>= 1) {
#pragma unroll
      for (int j = (k & (p - 1)); j + k < 32; j += 2 * k) {
#pragma unroll
        for (int t = 0; t < k; ++t) {
          if ((t + j) / (2 * p) == (t + j + k) / (2 * p)) {
            u64 a = key[t + j], bb2 = key[t + j + k];
            u64 lo = a < bb2 ? a : bb2;
            u64 hi = a < bb2 ? bb2 : a;
            key[t + j] = lo;
            key[t + j + k] = hi;
          }
        }
      }
    }
  }

#pragma unroll
  for (int r = 0; r < 32; ++r) lds[lane * 33 + r] = key[r];
  lds[lane * 33 + 32] = ~0ull;   // sentinel

  u64 cur = key[0];
  int h = 0;
  int* op = idx_out + (size_t)pid * KK;
#pragma unroll 1
  for (int r = 0; r < KK; ++r) {
    u64 m = cur;
#pragma unroll
    for (int s = 1; s < 64; s <<= 1) {
      u64 o = __shfl_xor(m, s);
      m = (o < m) ? o : m;
    }
    if (lane == 0) op[r] = (int)(u32)(m & 0xffffffffu);
    if (cur == m) { ++h; cur = lds[lane * 33 + h]; }
  }
}

// ---------------------------------------------------------------------------
// Kernel 3: density weights. 2 points per wave (width-32 shfl), lane&31 = k.
// w = max(d16,eps)^3 normalized over the 32 neighbors. (Value-continuous:
// f32 selection noise perturbs the kth VALUE by <1e-6 — harmless.)
// ---------------------------------------------------------------------------
__global__ __launch_bounds__(64) void density_kernel(const float* __restrict__ coords,
                                                     const int* __restrict__ idxb,
                                                     float* __restrict__ wbuf) {
  const int lane = threadIdx.x;
  const int half = lane >> 5;
  const int k = lane & 31;
  const int pid = blockIdx.x * 2 + half;   // b*N + i
  const int b = pid >> 11;
  const float* cb = coords + (size_t)b * NN * 3;
  int j = idxb[(size_t)pid * KK + k];
  float nx = cb[j * 3 + 0], ny = cb[j * 3 + 1], nz = cb[j * 3 + 2];
  float sme = refsq3(nx, ny, nz);

  float d[32];
#pragma unroll
  for (int t = 0; t < 32; ++t) {
    float ox = __shfl(nx, t, 32);
    float oy = __shfl(ny, t, 32);
    float oz = __shfl(nz, t, 32);
    float so = refsq3(ox, oy, oz);
    float dt = refdot3(nx, ny, nz, ox, oy, oz);
    float dd = refdist(sme, so, dt);
    d[t] = (t == k) ? INFINITY : dd;   // eye mask
  }

  // sort 32 f32 ascending (values only; ties don't matter for the k-th VALUE)
#pragma unroll
  for (int p = 1; p < 32; p <<= 1) {
#pragma unroll
    for (int kk = p; kk >= 1; kk >>= 1) {
#pragma unroll
      for (int jj = (kk & (p - 1)); jj + kk < 32; jj += 2 * kk) {
#pragma unroll
        for (int t = 0; t < kk; ++t) {
          if ((t + jj) / (2 * p) == (t + jj + kk) / (2 * p)) {
            float a = d[t + jj], b2 = d[t + jj + kk];
            float lo = fminf(a, b2);
            float hi = fmaxf(a, b2);
            d[t + jj] = lo;
            d[t + jj + kk] = hi;
          }
        }
      }
    }
  }

  float kth = d[DK - 1];                 // 16th smallest (diag inf sorts last)
  float r1 = fmaxf(kth, EPSF);
  float raw = __fmul_rn(__fmul_rn(r1, r1), r1);
  float s = raw;
#pragma unroll
  for (int t = 1; t < 32; t <<= 1) s += __shfl_xor(s, t, 32);
  wbuf[(size_t)pid * KK + k] = raw / fmaxf(s, EPSF);
}

// ---------------------------------------------------------------------------
// Kernel 4: aggregation. One wave/point, lane = channel.
// out[b,c,i] = sum_k w_k * relu(G[b,j_k,c] + invW_rel[c]·rel_k)
// ---------------------------------------------------------------------------
__global__ __launch_bounds__(256) void agg_kernel(
    const float* __restrict__ coords, const float* __restrict__ conv_w,
    const float* __restrict__ gamma, const float* __restrict__ var,
    const float* __restrict__ G, const int* __restrict__ idxb,
    const float* __restrict__ wbuf, float* __restrict__ out) {
  const int lane = threadIdx.x & 63;
  const int wv = threadIdx.x >> 6;
  const int pid = blockIdx.x * 4 + wv;   // b*N + i
  const int b = pid >> 11;
  const int i = pid & (NN - 1);
  const float* cb = coords + (size_t)b * NN * 3;

  float inv = __fdiv_rn(gamma[lane], __fsqrt_rn(__fadd_rn(var[lane], BN_EPSF)));
  float w0 = conv_w[lane * (CC + 3) + 0] * inv;
  float w1 = conv_w[lane * (CC + 3) + 1] * inv;
  float w2 = conv_w[lane * (CC + 3) + 2] * inv;

  float cx = cb[i * 3 + 0], cy = cb[i * 3 + 1], cz = cb[i * 3 + 2];
  float rx = 0.f, ry = 0.f, rz = 0.f, wk = 0.f;
  int jk = 0;
  if (lane < 32) {
    jk = idxb[(size_t)pid * KK + lane];
    rx = __fdiv_rn(__fsub_rn(cb[jk * 3 + 0], cx), RADIUSF);
    ry = __fdiv_rn(__fsub_rn(cb[jk * 3 + 1], cy), RADIUSF);
    rz = __fdiv_rn(__fsub_rn(cb[jk * 3 + 2], cz), RADIUSF);
    wk = wbuf[(size_t)pid * KK + lane];
  }

  float acc = 0.f;
#pragma unroll
  for (int k = 0; k < KK; ++k) {
    int j = __shfl(jk, k);
    float sx = __shfl(rx, k);
    float sy = __shfl(ry, k);
    float sz = __shfl(rz, k);
    float sw = __shfl(wk, k);
    float g = G[((size_t)(b * NN + j)) * 64 + lane];
    float y = fmaf(w2, sz, fmaf(w1, sy, fmaf(w0, sx, g)));
    y = fmaxf(y, 0.f);
    acc = fmaf(sw, y, acc);
  }
  out[((size_t)(b * 64 + lane)) * NN + i] = acc;
}

// ---------------------------------------------------------------------------
extern "C" void kernel_launch(void* const* d_in, const int* in_sizes, int n_in,
                              void* d_out, int out_size, void* d_ws, size_t ws_size,
                              hipStream_t stream) {
  const float* coords = (const float*)d_in[0];
  const float* feats  = (const float*)d_in[1];
  const float* conv_w = (const float*)d_in[2];
  const float* gamma  = (const float*)d_in[3];
  const float* beta   = (const float*)d_in[4];
  const float* mean   = (const float*)d_in[5];
  const float* var    = (const float*)d_in[6];
  float* out = (float*)d_out;

  int*   idxb = (int*)d_ws;                                          // 2 MB
  float* wbuf = (float*)((char*)d_ws + (size_t)2 * 1024 * 1024);     // 2 MB
  float* G    = (float*)((char*)d_ws + (size_t)4 * 1024 * 1024);     // 4 MB

  const int NPTS = BB * NN;   // 16384

  knn_kernel<<<NPTS, 64, 0, stream>>>(coords, idxb);
  gfeat_kernel<<<(NPTS * CC) / 256, 256, 0, stream>>>(feats, conv_w, gamma, beta,
                                                      mean, var, G);
  density_kernel<<<NPTS / 2, 64, 0, stream>>>(coords, idxb, wbuf);
  agg_kernel<<<NPTS / 4, 256, 0, stream>>>(coords, conv_w, gamma, var, G, idxb,
                                           wbuf, out);
}

// Round 4
// 183.260 us; speedup vs baseline: 1.1330x; 1.1330x over previous
//
#include <hip/hip_runtime.h>
#include <stdint.h>

#define BB 8
#define NN 2048
#define CC 64
#define KK 32
#define DK 16
#define RADIUSF 0.2f
#define EPSF 1e-8f
#define BN_EPSF 1e-5f

typedef unsigned long long u64;
typedef unsigned int u32;
typedef unsigned char u8;

// --- fp32 helpers matching the reference's arithmetic ---
// sum of squares: elementwise square (rounded) then sequential reduce — no FMA
__device__ __forceinline__ float refsq3(float a, float b, float c) {
  return __fadd_rn(__fadd_rn(__fmul_rn(a, a), __fmul_rn(b, b)), __fmul_rn(c, c));
}
// einsum dot: BLAS/Eigen/XLA style acc = fma(a_k, b_k, acc), k ascending
__device__ __forceinline__ float refdot3(float ax, float ay, float az,
                                         float bx, float by, float bz) {
  return __builtin_fmaf(az, bz, __builtin_fmaf(ay, by, __fmul_rn(ax, bx)));
}
__device__ __forceinline__ float refdist(float sx, float sy, float dt) {
  float d2 = __fsub_rn(__fadd_rn(sx, sy), __fmul_rn(2.0f, dt));
  d2 = fmaxf(d2, 0.0f);
  return d2 > 0.0f ? __fsqrt_rn(d2) : 0.0f;
}

// ---------------------------------------------------------------------------
// Kernel 0: pack coords + exact ref-rounded sq-norm into float4 (x,y,z,sn).
// ---------------------------------------------------------------------------
__global__ __launch_bounds__(256) void pack_kernel(const float* __restrict__ coords,
                                                   float4* __restrict__ P) {
  int t = blockIdx.x * 256 + threadIdx.x;   // 0..16383
  float x = coords[t * 3 + 0], y = coords[t * 3 + 1], z = coords[t * 3 + 2];
  P[t] = make_float4(x, y, z, refsq3(x, y, z));
}

// ---------------------------------------------------------------------------
// Kernel 1: G[b][n][c] = inv[c]*(W_f[c,:]·feats[b,:,n]) + shift[c]
// W staged in LDS padded [64][65] so lane-varying reads are 2-way (free).
// feats reads are wave-broadcast (same address) — 1 L1 transaction each.
// ---------------------------------------------------------------------------
__global__ __launch_bounds__(256) void gfeat_kernel(
    const float* __restrict__ feats, const float* __restrict__ conv_w,
    const float* __restrict__ gamma, const float* __restrict__ beta,
    const float* __restrict__ mean, const float* __restrict__ var,
    float* __restrict__ G) {
  __shared__ float wlds[64 * 65];
  for (int e = threadIdx.x; e < 4096; e += 256) {
    int c = e >> 6, cp = e & 63;
    wlds[c * 65 + cp] = conv_w[c * (CC + 3) + 3 + cp];
  }
  __syncthreads();
  int t = blockIdx.x * 256 + threadIdx.x;   // t = m*64 + c
  int c = t & 63;
  int m = t >> 6;                            // b*N + n
  int b = m >> 11;
  int n = m & (NN - 1);
  float inv = __fdiv_rn(gamma[c], __fsqrt_rn(__fadd_rn(var[c], BN_EPSF)));
  float shift = __fsub_rn(beta[c], __fmul_rn(mean[c], inv));
  const float* f = feats + (size_t)b * CC * NN + n;   // stride NN over c'
  float acc = 0.f;
#pragma unroll
  for (int cp = 0; cp < CC; ++cp) acc = fmaf(wlds[c * 65 + cp], f[(size_t)cp * NN], acc);
  G[t] = fmaf(inv, acc, shift);
}

// ---------------------------------------------------------------------------
// Kernel 2: exact KNN (== reference ball query). One wave per query.
// Candidates via coalesced float4 loads (norm precomputed). Selection keys
// (bits(f32 sqrt dist)<<32)|j — FMA-LTR dot bit-matches the reference.
// Merge staging slimmed to u32 dist + u8 c (j = c*64+lane) -> 10.2 KB LDS.
// ---------------------------------------------------------------------------
__global__ __launch_bounds__(64, 4) void knn_kernel(const float4* __restrict__ P,
                                                    int* __restrict__ idx_out) {
  __shared__ u32 lds_d[32 * 64];
  __shared__ u8 lds_c[32 * 64];
  const int lane = threadIdx.x;
  const int pid = blockIdx.x;          // b*N + i
  const int b = pid >> 11;
  const int i = pid & (NN - 1);
  const float4* Pb = P + ((size_t)b << 11);
  float4 q = Pb[i];

  u64 key[32];
#pragma unroll
  for (int c = 0; c < 32; ++c) {
    int j = (c << 6) | lane;
    float4 p = Pb[j];
    float dt = refdot3(q.x, q.y, q.z, p.x, p.y, p.z);
    float d = refdist(q.w, p.w, dt);
    key[c] = ((u64)__float_as_uint(d) << 32) | (u32)j;
  }

  // Batcher odd-even mergesort, n=32, ascending, static indices (VGPRs only)
#pragma unroll
  for (int p = 1; p < 32; p <<= 1) {
#pragma unroll
    for (int k = p; k >= 1; k >>= 1) {
#pragma unroll
      for (int j = (k & (p - 1)); j + k < 32; j += 2 * k) {
#pragma unroll
        for (int t = 0; t < k; ++t) {
          if ((t + j) / (2 * p) == (t + j + k) / (2 * p)) {
            u64 a = key[t + j], bb2 = key[t + j + k];
            u64 lo = a < bb2 ? a : bb2;
            u64 hi = a < bb2 ? bb2 : a;
            key[t + j] = lo;
            key[t + j + k] = hi;
          }
        }
      }
    }
  }

  // slim staging: dist bits + candidate-slot byte (j = (c<<6)|lane)
#pragma unroll
  for (int r = 0; r < 32; ++r) {
    lds_d[(r << 6) | lane] = (u32)(key[r] >> 32);
    lds_c[(r << 6) | lane] = (u8)(((u32)key[r]) >> 6);
  }

  u64 cur = key[0];
  int h = 0;
  int* op = idx_out + (size_t)pid * KK;
#pragma unroll 1
  for (int r = 0; r < KK; ++r) {
    u64 m = cur;
#pragma unroll
    for (int s = 1; s < 64; s <<= 1) {
      u64 o = __shfl_xor(m, s);
      m = (o < m) ? o : m;
    }
    if (lane == 0) op[r] = (int)(u32)m;   // low 32 bits = j
    if (cur == m) {
      ++h;
      if (h < 32) {
        u32 dd = lds_d[(h << 6) | lane];
        u32 cc = lds_c[(h << 6) | lane];
        cur = ((u64)dd << 32) | (u64)((cc << 6) | lane);
      } else {
        cur = ~0ull;
      }
    }
  }
}

// ---------------------------------------------------------------------------
// Kernel 3: density weights. 2 points per wave (width-32 shfl), lane&31 = k.
// ---------------------------------------------------------------------------
__global__ __launch_bounds__(64) void density_kernel(const float* __restrict__ coords,
                                                     const int* __restrict__ idxb,
                                                     float* __restrict__ wbuf) {
  const int lane = threadIdx.x;
  const int half = lane >> 5;
  const int k = lane & 31;
  const int pid = blockIdx.x * 2 + half;   // b*N + i
  const int b = pid >> 11;
  const float* cb = coords + (size_t)b * NN * 3;
  int j = idxb[(size_t)pid * KK + k];
  float nx = cb[j * 3 + 0], ny = cb[j * 3 + 1], nz = cb[j * 3 + 2];
  float sme = refsq3(nx, ny, nz);

  float d[32];
#pragma unroll
  for (int t = 0; t < 32; ++t) {
    float ox = __shfl(nx, t, 32);
    float oy = __shfl(ny, t, 32);
    float oz = __shfl(nz, t, 32);
    float so = refsq3(ox, oy, oz);
    float dt = refdot3(nx, ny, nz, ox, oy, oz);
    float dd = refdist(sme, so, dt);
    d[t] = (t == k) ? INFINITY : dd;   // eye mask
  }

#pragma unroll
  for (int p = 1; p < 32; p <<= 1) {
#pragma unroll
    for (int kk = p; kk >= 1; kk >>= 1) {
#pragma unroll
      for (int jj = (kk & (p - 1)); jj + kk < 32; jj += 2 * kk) {
#pragma unroll
        for (int t = 0; t < kk; ++t) {
          if ((t + jj) / (2 * p) == (t + jj + kk) / (2 * p)) {
            float a = d[t + jj], b2 = d[t + jj + kk];
            float lo = fminf(a, b2);
            float hi = fmaxf(a, b2);
            d[t + jj] = lo;
            d[t + jj + kk] = hi;
          }
        }
      }
    }
  }

  float kth = d[DK - 1];                 // 16th smallest (diag inf sorts last)
  float r1 = fmaxf(kth, EPSF);
  float raw = __fmul_rn(__fmul_rn(r1, r1), r1);
  float s = raw;
#pragma unroll
  for (int t = 1; t < 32; t <<= 1) s += __shfl_xor(s, t, 32);
  wbuf[(size_t)pid * KK + k] = raw / fmaxf(s, EPSF);
}

// ---------------------------------------------------------------------------
// Kernel 4: aggregation. One wave/point, lane = channel.
// ---------------------------------------------------------------------------
__global__ __launch_bounds__(256) void agg_kernel(
    const float* __restrict__ coords, const float* __restrict__ conv_w,
    const float* __restrict__ gamma, const float* __restrict__ var,
    const float* __restrict__ G, const int* __restrict__ idxb,
    const float* __restrict__ wbuf, float* __restrict__ out) {
  const int lane = threadIdx.x & 63;
  const int wv = threadIdx.x >> 6;
  const int pid = blockIdx.x * 4 + wv;   // b*N + i
  const int b = pid >> 11;
  const int i = pid & (NN - 1);
  const float* cb = coords + (size_t)b * NN * 3;

  float inv = __fdiv_rn(gamma[lane], __fsqrt_rn(__fadd_rn(var[lane], BN_EPSF)));
  float w0 = conv_w[lane * (CC + 3) + 0] * inv;
  float w1 = conv_w[lane * (CC + 3) + 1] * inv;
  float w2 = conv_w[lane * (CC + 3) + 2] * inv;

  float cx = cb[i * 3 + 0], cy = cb[i * 3 + 1], cz = cb[i * 3 + 2];
  float rx = 0.f, ry = 0.f, rz = 0.f, wk = 0.f;
  int jk = 0;
  if (lane < 32) {
    jk = idxb[(size_t)pid * KK + lane];
    rx = __fdiv_rn(__fsub_rn(cb[jk * 3 + 0], cx), RADIUSF);
    ry = __fdiv_rn(__fsub_rn(cb[jk * 3 + 1], cy), RADIUSF);
    rz = __fdiv_rn(__fsub_rn(cb[jk * 3 + 2], cz), RADIUSF);
    wk = wbuf[(size_t)pid * KK + lane];
  }

  float acc = 0.f;
#pragma unroll
  for (int k = 0; k < KK; ++k) {
    int j = __shfl(jk, k);
    float sx = __shfl(rx, k);
    float sy = __shfl(ry, k);
    float sz = __shfl(rz, k);
    float sw = __shfl(wk, k);
    float g = G[((size_t)(b * NN + j)) * 64 + lane];
    float y = fmaf(w2, sz, fmaf(w1, sy, fmaf(w0, sx, g)));
    y = fmaxf(y, 0.f);
    acc = fmaf(sw, y, acc);
  }
  out[((size_t)(b * 64 + lane)) * NN + i] = acc;
}

// ---------------------------------------------------------------------------
extern "C" void kernel_launch(void* const* d_in, const int* in_sizes, int n_in,
                              void* d_out, int out_size, void* d_ws, size_t ws_size,
                              hipStream_t stream) {
  const float* coords = (const float*)d_in[0];
  const float* feats  = (const float*)d_in[1];
  const float* conv_w = (const float*)d_in[2];
  const float* gamma  = (const float*)d_in[3];
  const float* beta   = (const float*)d_in[4];
  const float* mean   = (const float*)d_in[5];
  const float* var    = (const float*)d_in[6];
  float* out = (float*)d_out;

  int*   idxb = (int*)d_ws;                                          // 2 MB
  float* wbuf = (float*)((char*)d_ws + (size_t)2 * 1024 * 1024);     // 2 MB
  float* G    = (float*)((char*)d_ws + (size_t)4 * 1024 * 1024);     // 4 MB
  // P aliases the G region: knn consumes P before gfeat overwrites G.
  float4* P   = (float4*)G;                                          // 256 KB

  const int NPTS = BB * NN;   // 16384

  pack_kernel<<<NPTS / 256, 256, 0, stream>>>(coords, P);
  knn_kernel<<<NPTS, 64, 0, stream>>>(P, idxb);
  gfeat_kernel<<<(NPTS * CC) / 256, 256, 0, stream>>>(feats, conv_w, gamma, beta,
                                                      mean, var, G);
  density_kernel<<<NPTS / 2, 64, 0, stream>>>(coords, idxb, wbuf);
  agg_kernel<<<NPTS / 4, 256, 0, stream>>>(coords, conv_w, gamma, var, G, idxb,
                                           wbuf, out);
}